// Round 2
// baseline (102518.823 us; speedup 1.0000x reference)
//
#include <hip/hip_runtime.h>
#include <math.h>

// Problem constants
constexpr int H   = 256;
constexpr int B   = 64;
constexpr int T   = 2048;
constexpr int G   = 64;    // blocks
constexpr int NTH = 512;   // threads per block (8 waves)
constexpr int HB  = H * B; // 16384
constexpr int W   = 2;     // slot window for per-step counters (skew <= 1)

struct SharedMain {
    float wU[256][16];   // W_ih slice, [k][cl], cl = gate*4+oi
    float wV[256][16];   // W_hh slice
    float wA[768][4];    // W_e (rows 0..511) + W_b (rows 512..767), [r][i]
    float U[64][17];     // x@W_ih^T partial results (padded)
    float V[64][17];     // h@W_hh^T
    float ap[64][5];     // 'a' partials (pre-tanh), padded
    alignas(16) float outst[64][4];  // output staging
    float jp[8][64];     // per-wave j partial sums
    float bg[16];        // b_ih+b_hh slice
    float ba[4];         // b_e+b_b slice
    float v4[4];         // v_b slice
    float s[64];         // softmax weights
};
union SharedAll {
    SharedMain m;
    float tile[64][65];  // transpose staging (aliases weights; used first)
};

__device__ __forceinline__ float sigmoidf_(float v) {
    return 1.0f / (1.0f + expf(-v));
}

// --- sync primitives: RELAXED polling (no per-poll L2 invalidate!) ---
__device__ __forceinline__ void fence_rel() { __builtin_amdgcn_fence(__ATOMIC_RELEASE, "agent"); }
__device__ __forceinline__ void fence_acq() { __builtin_amdgcn_fence(__ATOMIC_ACQUIRE, "agent"); }

__device__ __forceinline__ void arrive(unsigned* c) {
    fence_rel();  // flush this block's prior stores to the coherent point
    __hip_atomic_fetch_add(c, 1u, __ATOMIC_RELAXED, __HIP_MEMORY_SCOPE_AGENT);
}
__device__ __forceinline__ void wait_for(unsigned* c, unsigned target) {
    while (__hip_atomic_load(c, __ATOMIC_RELAXED, __HIP_MEMORY_SCOPE_AGENT) < target)
        __builtin_amdgcn_s_sleep(1);
    fence_acq();  // ONE invalidate after success
}

__global__ void __launch_bounds__(NTH, 1)
scan_kernel(const float* __restrict__ x,
            const float* __restrict__ W_b,  const float* __restrict__ b_b,
            const float* __restrict__ v_b,  const float* __restrict__ W_e,
            const float* __restrict__ b_e,  const float* __restrict__ W_ih,
            const float* __restrict__ W_hh, const float* __restrict__ b_ih,
            const float* __restrict__ b_hh,
            float* __restrict__ out, float* __restrict__ wsf)
{
    __shared__ SharedAll sh;
    const int tid = threadIdx.x;
    const int g   = blockIdx.x;

    unsigned* cnt = (unsigned*)wsf;
    unsigned* bar = cnt + 0;
    unsigned* dj0 = cnt + 16;  // done_j slot0 (64B spacing)
    unsigned* dj1 = cnt + 32;
    unsigned* dh0 = cnt + 48;  // done_hc slot0
    unsigned* dh1 = cnt + 64;

    float* pJ = wsf + 128;          // [W][G][64] j partials
    float* hT = pJ + W * G * 64;    // [H][B] transposed h state
    float* cT = hT + HB;            // [H][B] transposed c state
    float* xT = out;                // reuse output buffer (xT[t] dead before out[t] write)

    // ---------- Phase 0: transpose x[t][b][k] -> xT[t][k][b] ----------
    for (int tl = g; tl < T * 4; tl += G) {
        const int t  = tl >> 2;
        const int kc = (tl & 3) << 6;
        __syncthreads();
        for (int q = tid; q < 1024; q += NTH) {
            const int r  = q >> 4;
            const int c4 = (q & 15) << 2;
            const float4 v = *(const float4*)(x + (size_t)t * HB + (size_t)r * H + kc + c4);
            sh.tile[r][c4 + 0] = v.x; sh.tile[r][c4 + 1] = v.y;
            sh.tile[r][c4 + 2] = v.z; sh.tile[r][c4 + 3] = v.w;
        }
        __syncthreads();
        for (int q = tid; q < 1024; q += NTH) {
            const int k  = q >> 4;
            const int b4 = (q & 15) << 2;
            float4 v;
            v.x = sh.tile[b4 + 0][k]; v.y = sh.tile[b4 + 1][k];
            v.z = sh.tile[b4 + 2][k]; v.w = sh.tile[b4 + 3][k];
            *(float4*)(xT + (size_t)t * HB + (size_t)(kc + k) * B + b4) = v;
        }
    }
    __syncthreads();

    // ---------- Phase 1: weights -> LDS (block owns h-cols 4g..4g+3) ----------
    for (int e = tid; e < 256 * 16; e += NTH) {
        const int k  = e >> 4;
        const int cl = e & 15;
        const int gate = cl >> 2, oi = cl & 3;
        const int row = gate * H + 4 * g + oi;
        sh.m.wU[k][cl] = W_ih[(size_t)row * H + k];
        sh.m.wV[k][cl] = W_hh[(size_t)row * H + k];
    }
    for (int e = tid; e < 768 * 4; e += NTH) {
        const int r = e >> 2;
        const int i = e & 3;
        const int col = 4 * g + i;
        float w;
        if (r < 512) w = W_e[(size_t)col * 512 + r];
        else         w = W_b[(size_t)col * 256 + (r - 512)];
        sh.m.wA[r][i] = w;
    }
    if (tid < 16) {
        const int gate = tid >> 2, oi = tid & 3;
        const int col = gate * H + 4 * g + oi;
        sh.m.bg[tid] = b_ih[col] + b_hh[col];
    }
    if (tid < 4) {
        sh.m.ba[tid] = b_e[4 * g + tid] + b_b[4 * g + tid];
        sh.m.v4[tid] = v_b[4 * g + tid];
    }
    // zero h,c (hT and cT contiguous: 32768 floats == G*NTH)
    hT[g * NTH + tid] = 0.0f;

    // one-time grid barrier (setup complete)
    __threadfence_block();
    __syncthreads();
    if (tid == 0) { arrive(bar); wait_for(bar, (unsigned)G); }
    __syncthreads();

    const int wv = tid >> 6;   // wave 0..7
    const int b  = tid & 63;   // lane = batch index

    // ---------- Main scan: split arrive/wait, 1-step max skew ----------
    for (int t = 0; t < T; ++t) {
        const int slot = t & 1;
        unsigned* dj = slot ? dj1 : dj0;
        const unsigned tgt = (unsigned)G * ((unsigned)(t >> 1) + 1u);

        // zero accumulators
        for (int e = tid; e < 64 * 17; e += NTH) { (&sh.m.U[0][0])[e] = 0.0f; (&sh.m.V[0][0])[e] = 0.0f; }
        for (int e = tid; e < 64 * 5; e += NTH) (&sh.m.ap[0][0])[e] = 0.0f;
        __syncthreads();

        // ---- Stage A (state-independent): U = x_t@W_ih^T slice + a x-part ----
        {
            const int kw = wv << 5;  // 32 k-rows per wave
            const float* src = xT + (size_t)t * HB + (size_t)kw * B;
            float aU[16], aA[4];
            #pragma unroll
            for (int c = 0; c < 16; ++c) aU[c] = 0.0f;
            aA[0] = aA[1] = aA[2] = aA[3] = 0.0f;
            #pragma unroll 4
            for (int kk = 0; kk < 32; ++kk) {
                const float xv = src[kk * B + b];
                const float* wr = sh.m.wU[kw + kk];
                #pragma unroll
                for (int c = 0; c < 16; ++c) aU[c] = fmaf(xv, wr[c], aU[c]);
                const float* wa = sh.m.wA[512 + kw + kk];
                #pragma unroll
                for (int i = 0; i < 4; ++i) aA[i] = fmaf(xv, wa[i], aA[i]);
            }
            #pragma unroll
            for (int c = 0; c < 16; ++c) atomicAdd(&sh.m.U[b][c], aU[c]);
            #pragma unroll
            for (int i = 0; i < 4; ++i) atomicAdd(&sh.m.ap[b][i], aA[i]);
        }

        // ---- wait for h,c(t-1) from all blocks ----
        if (tid == 0 && t > 0) {
            unsigned* dh = ((t - 1) & 1) ? dh1 : dh0;
            wait_for(dh, (unsigned)G * ((unsigned)((t - 1) >> 1) + 1u));
        }
        __syncthreads();

        // ---- Stage B: V = h@W_hh^T slice + a h/c-part ----
        {
            const int kw = wv << 5;
            const float* sH = hT + (size_t)kw * B;
            const float* sC = cT + (size_t)kw * B;
            float aV[16], aA[4];
            #pragma unroll
            for (int c = 0; c < 16; ++c) aV[c] = 0.0f;
            aA[0] = aA[1] = aA[2] = aA[3] = 0.0f;
            #pragma unroll 4
            for (int kk = 0; kk < 32; ++kk) {
                const float hv = sH[kk * B + b];
                const float cv = sC[kk * B + b];
                const float* wr = sh.m.wV[kw + kk];
                #pragma unroll
                for (int c = 0; c < 16; ++c) aV[c] = fmaf(hv, wr[c], aV[c]);
                const float* waH = sh.m.wA[kw + kk];
                const float* waC = sh.m.wA[256 + kw + kk];
                #pragma unroll
                for (int i = 0; i < 4; ++i) aA[i] = fmaf(hv, waH[i], fmaf(cv, waC[i], aA[i]));
            }
            #pragma unroll
            for (int c = 0; c < 16; ++c) atomicAdd(&sh.m.V[b][c], aV[c]);
            #pragma unroll
            for (int i = 0; i < 4; ++i) atomicAdd(&sh.m.ap[b][i], aA[i]);
        }
        __syncthreads();

        // ---- finish 'a': tanh, dot v -> per-block j partial, publish ----
        if (tid < 64) {
            float pj = 0.0f;
            #pragma unroll
            for (int i = 0; i < 4; ++i)
                pj += tanhf(sh.m.ap[tid][i] + sh.m.ba[i]) * sh.m.v4[i];
            pJ[(size_t)slot * G * 64 + g * 64 + tid] = pj;
            __threadfence_block();
        }
        __syncthreads();
        if (tid == 0) { arrive(dj); wait_for(dj, tgt); }
        __syncthreads();

        // ---- reduce j across blocks, softmax over batch ----
        {
            float jpart = 0.0f;
            const int base = wv * 8;
            const float* pjs = pJ + (size_t)slot * G * 64;
            #pragma unroll
            for (int gg = 0; gg < 8; ++gg) jpart += pjs[(base + gg) * 64 + b];
            sh.m.jp[wv][b] = jpart;
        }
        __syncthreads();
        if (tid < 64) {
            float jv = 0.0f;
            #pragma unroll
            for (int w = 0; w < 8; ++w) jv += sh.m.jp[w][tid];
            float mx = jv;
            #pragma unroll
            for (int off = 32; off; off >>= 1) mx = fmaxf(mx, __shfl_xor(mx, off));
            const float e = expf(jv - mx);
            float ssum = e;
            #pragma unroll
            for (int off = 32; off; off >>= 1) ssum += __shfl_xor(ssum, off);
            sh.m.s[tid] = e / ssum;
        }
        __syncthreads();

        // ---- gates + LSTM update for our 4 h-columns, publish h,c(t) ----
        if (tid < 256) {
            const int oi = tid >> 6;
            const int bb = tid & 63;
            const float sb = sh.m.s[bb];
            const float pI = fmaf(sb, sh.m.U[bb][0  + oi], sh.m.V[bb][0  + oi]) + sh.m.bg[0  + oi];
            const float pF = fmaf(sb, sh.m.U[bb][4  + oi], sh.m.V[bb][4  + oi]) + sh.m.bg[4  + oi];
            const float pG = fmaf(sb, sh.m.U[bb][8  + oi], sh.m.V[bb][8  + oi]) + sh.m.bg[8  + oi];
            const float pO = fmaf(sb, sh.m.U[bb][12 + oi], sh.m.V[bb][12 + oi]) + sh.m.bg[12 + oi];
            const int col = 4 * g + oi;
            const float cold = cT[col * B + bb];
            const float cnew = sigmoidf_(pF) * cold + sigmoidf_(pI) * tanhf(pG);
            const float hnew = sigmoidf_(pO) * tanhf(cnew);
            cT[col * B + bb] = cnew;
            hT[col * B + bb] = hnew;
            sh.m.outst[bb][oi] = hnew;
            __threadfence_block();
        }
        __syncthreads();
        if (tid == 0) arrive(slot ? dh1 : dh0);

        // out write: safe after done_j[t]==G (all blocks done reading xT[t])
        if (tid < 64) {
            const float4 v = *(const float4*)sh.m.outst[tid];
            *(float4*)(out + (size_t)t * HB + (size_t)tid * H + 4 * g) = v;
        }
    }
}

extern "C" void kernel_launch(void* const* d_in, const int* in_sizes, int n_in,
                              void* d_out, int out_size, void* d_ws, size_t ws_size,
                              hipStream_t stream) {
    const float* x    = (const float*)d_in[0];
    const float* W_b  = (const float*)d_in[1];
    const float* b_b  = (const float*)d_in[2];
    const float* v_b  = (const float*)d_in[3];
    const float* W_e  = (const float*)d_in[4];
    const float* b_e  = (const float*)d_in[5];
    const float* W_ih = (const float*)d_in[6];
    const float* W_hh = (const float*)d_in[7];
    const float* b_ih = (const float*)d_in[8];
    const float* b_hh = (const float*)d_in[9];
    float*    out = (float*)d_out;
    float*    wsf = (float*)d_ws;

    // zero counters (bar + per-step slots); ws is re-poisoned before every launch
    hipMemsetAsync(d_ws, 0, 512, stream);

    void* args[] = { &x, &W_b, &b_b, &v_b, &W_e, &b_e, &W_ih, &W_hh, &b_ih, &b_hh,
                     &out, &wsf };
    hipLaunchCooperativeKernel((void*)scan_kernel, dim3(G), dim3(NTH), args, 0, stream);
}

// Round 3
// 95870.813 us; speedup vs baseline: 1.0693x; 1.0693x over previous
//
#include <hip/hip_runtime.h>
#include <math.h>

// Problem constants
constexpr int H   = 256;
constexpr int B   = 64;
constexpr int T   = 2048;
constexpr int G   = 64;    // blocks
constexpr int NTH = 512;   // threads per block (8 waves)
constexpr int HB  = H * B; // 16384

// ws layout (32-bit word indices)
constexpr int OFF_BAR = 0;               // one-time barrier counter (64B pad)
constexpr int OFF_DJ  = 16;              // dj[t] at OFF_DJ + t*8 (32B stride)
constexpr int OFF_DH  = OFF_DJ + T * 8;  // dh[t] at OFF_DH + t*8
constexpr int OFF_PJ  = OFF_DH + T * 8;  // pJ[2][G][64] floats
constexpr int OFF_HT  = OFF_PJ + 2 * G * 64;
constexpr int OFF_CT  = OFF_HT + HB;
// end = OFF_CT + HB = 73744 words ~= 295 KB of ws

struct SharedMain {
    float wU[256][16];   // W_ih slice, [k][cl], cl = gate*4+oi
    float wV[256][16];   // W_hh slice
    float wA[768][4];    // W_e rows 0..511 (h then c), W_b rows 512..767
    float U[64][17];     // x@W_ih^T partials (padded)
    float V[64][17];     // h@W_hh^T partials
    float ap[64][5];     // 'a' partials (pre-tanh), padded
    alignas(16) float outst[64][4];  // h_new staging [b][oi]
    float c_own[4][64];  // this block's 4 c-columns [oi][b]
    float bg[16];        // b_ih+b_hh slice
    float ba[4];         // b_e+b_b slice
    float v4[4];         // v_b slice
    float s[64];         // softmax weights
};
union SharedAll {
    SharedMain m;
    float tile[64][65];  // transpose staging (aliases weights; used first)
};

__device__ __forceinline__ float sigmoidf_(float v) {
    return 1.0f / (1.0f + expf(-v));
}

// ---- coherence-point (LLC) access primitives: no cache maintenance ops ----
__device__ __forceinline__ unsigned ld_rlx_u32(const unsigned* p) {
    return __hip_atomic_load(p, __ATOMIC_RELAXED, __HIP_MEMORY_SCOPE_AGENT);
}
__device__ __forceinline__ float ld_rlx_f32(const float* p) {
    return __hip_atomic_load(p, __ATOMIC_RELAXED, __HIP_MEMORY_SCOPE_AGENT);
}
__device__ __forceinline__ void st_rlx_f32(float* p, float v) {
    __hip_atomic_store(p, v, __ATOMIC_RELAXED, __HIP_MEMORY_SCOPE_AGENT);
}
__device__ __forceinline__ void add_rlx_u32(unsigned* p, unsigned v) {
    __hip_atomic_fetch_add(p, v, __ATOMIC_RELAXED, __HIP_MEMORY_SCOPE_AGENT);
}
__device__ __forceinline__ void waitcnt_vm() {
    asm volatile("s_waitcnt vmcnt(0)" ::: "memory");
}

// one-time barrier with full fences (setup only)
__device__ __forceinline__ void fence_rel() { __builtin_amdgcn_fence(__ATOMIC_RELEASE, "agent"); }
__device__ __forceinline__ void fence_acq() { __builtin_amdgcn_fence(__ATOMIC_ACQUIRE, "agent"); }

__global__ void __launch_bounds__(NTH, 1)
scan_kernel(const float* __restrict__ x,
            const float* __restrict__ W_b,  const float* __restrict__ b_b,
            const float* __restrict__ v_b,  const float* __restrict__ W_e,
            const float* __restrict__ b_e,  const float* __restrict__ W_ih,
            const float* __restrict__ W_hh, const float* __restrict__ b_ih,
            const float* __restrict__ b_hh,
            float* __restrict__ out, float* __restrict__ wsf)
{
    __shared__ SharedAll sh;
    const int tid = threadIdx.x;
    const int g   = blockIdx.x;

    unsigned* cnt = (unsigned*)wsf;
    float* pJ = wsf + OFF_PJ;
    float* hT = wsf + OFF_HT;
    float* cT = wsf + OFF_CT;
    float* xT = out;   // reuse output buffer (xT[t] dead before out[t] write)

    // ---------- Phase 0: transpose x[t][b][k] -> xT[t][k][b] ----------
    for (int tl = g; tl < T * 4; tl += G) {
        const int t  = tl >> 2;
        const int kc = (tl & 3) << 6;
        __syncthreads();
        for (int q = tid; q < 1024; q += NTH) {
            const int r  = q >> 4;
            const int c4 = (q & 15) << 2;
            const float4 v = *(const float4*)(x + (size_t)t * HB + (size_t)r * H + kc + c4);
            sh.tile[r][c4 + 0] = v.x; sh.tile[r][c4 + 1] = v.y;
            sh.tile[r][c4 + 2] = v.z; sh.tile[r][c4 + 3] = v.w;
        }
        __syncthreads();
        for (int q = tid; q < 1024; q += NTH) {
            const int k  = q >> 4;
            const int b4 = (q & 15) << 2;
            float4 v;
            v.x = sh.tile[b4 + 0][k]; v.y = sh.tile[b4 + 1][k];
            v.z = sh.tile[b4 + 2][k]; v.w = sh.tile[b4 + 3][k];
            *(float4*)(xT + (size_t)t * HB + (size_t)(kc + k) * B + b4) = v;
        }
    }
    __syncthreads();

    // ---------- Phase 1: weights -> LDS; zero ws state/counters ----------
    for (int e = tid; e < 256 * 16; e += NTH) {
        const int k  = e >> 4;
        const int cl = e & 15;
        const int gate = cl >> 2, oi = cl & 3;
        const int row = gate * H + 4 * g + oi;
        sh.m.wU[k][cl] = W_ih[(size_t)row * H + k];
        sh.m.wV[k][cl] = W_hh[(size_t)row * H + k];
    }
    for (int e = tid; e < 768 * 4; e += NTH) {
        const int r = e >> 2;
        const int i = e & 3;
        const int col = 4 * g + i;
        float w;
        if (r < 512) w = W_e[(size_t)col * 512 + r];
        else         w = W_b[(size_t)col * 256 + (r - 512)];
        sh.m.wA[r][i] = w;
    }
    if (tid < 16) {
        const int gate = tid >> 2, oi = tid & 3;
        const int col = gate * H + 4 * g + oi;
        sh.m.bg[tid] = b_ih[col] + b_hh[col];
    }
    if (tid < 4) {
        sh.m.ba[tid] = b_e[4 * g + tid] + b_b[4 * g + tid];
        sh.m.v4[tid] = v_b[4 * g + tid];
    }
    if (tid < 256) sh.m.c_own[tid >> 6][tid & 63] = 0.0f;
    // zero hT+cT (contiguous 32768 = G*NTH) and counters (dj+dh = 2*T*8 = G*NTH)
    hT[g * NTH + tid] = 0.0f;
    cnt[OFF_DJ + g * NTH + tid] = 0u;

    // one-time grid barrier with full release/acquire (flush zeros & xT)
    __syncthreads();
    if (tid == 0) {
        fence_rel();
        add_rlx_u32(cnt + OFF_BAR, 1u);
        while (ld_rlx_u32(cnt + OFF_BAR) < (unsigned)G) __builtin_amdgcn_s_sleep(1);
        fence_acq();
    }
    __syncthreads();

    const int wv = tid >> 6;   // wave 0..7
    const int b  = tid & 63;   // lane = batch index

    // ---------- Main scan: fenceless, LLC-resident state ----------
    for (int t = 0; t < T; ++t) {
        unsigned* dj_t = cnt + OFF_DJ + t * 8;
        unsigned* dh_t = cnt + OFF_DH + t * 8;
        float*    pJs  = pJ + (size_t)(t & 1) * G * 64;

        // zero U, V, ap
        for (int e = tid; e < 64 * 17; e += NTH) { (&sh.m.U[0][0])[e] = 0.0f; (&sh.m.V[0][0])[e] = 0.0f; }
        for (int e = tid; e < 64 * 5; e += NTH) (&sh.m.ap[0][0])[e] = 0.0f;
        __syncthreads();   // S1

        // ---- Stage A (state-independent): U = x_t@W_ih^T + a x-part (cached) ----
        {
            const int kw = wv << 5;
            const float* src = xT + (size_t)t * HB + (size_t)kw * B;
            float aU[16], aA[4];
            #pragma unroll
            for (int c = 0; c < 16; ++c) aU[c] = 0.0f;
            aA[0] = aA[1] = aA[2] = aA[3] = 0.0f;
            #pragma unroll 4
            for (int kk = 0; kk < 32; ++kk) {
                const float xv = src[kk * B + b];
                const float* wr = sh.m.wU[kw + kk];
                #pragma unroll
                for (int c = 0; c < 16; ++c) aU[c] = fmaf(xv, wr[c], aU[c]);
                const float* wa = sh.m.wA[512 + kw + kk];
                #pragma unroll
                for (int i = 0; i < 4; ++i) aA[i] = fmaf(xv, wa[i], aA[i]);
            }
            #pragma unroll
            for (int c = 0; c < 16; ++c) atomicAdd(&sh.m.U[b][c], aU[c]);
            #pragma unroll
            for (int i = 0; i < 4; ++i) atomicAdd(&sh.m.ap[b][i], aA[i]);
        }

        // ---- wait for h,c(t-1): relaxed poll, NO fence ----
        if (tid == 0 && t > 0) {
            unsigned* dh_p = cnt + OFF_DH + (t - 1) * 8;
            while (ld_rlx_u32(dh_p) < (unsigned)G) __builtin_amdgcn_s_sleep(1);
        }
        __syncthreads();   // S2 (gates Stage B state reads behind the poll)

        // ---- Stage B: uncached state loads -> regs, then FMA ----
        {
            const int kw = wv << 5;
            const float* sH = hT + (size_t)kw * B + b;
            const float* sC = cT + (size_t)kw * B + b;
            float hreg[32], creg[32];
            #pragma unroll
            for (int kk = 0; kk < 32; ++kk) {
                hreg[kk] = ld_rlx_f32(sH + kk * B);
                creg[kk] = ld_rlx_f32(sC + kk * B);
            }
            float aV[16], aA[4];
            #pragma unroll
            for (int c = 0; c < 16; ++c) aV[c] = 0.0f;
            aA[0] = aA[1] = aA[2] = aA[3] = 0.0f;
            #pragma unroll 4
            for (int kk = 0; kk < 32; ++kk) {
                const float hv = hreg[kk];
                const float cv = creg[kk];
                const float* wr = sh.m.wV[kw + kk];
                #pragma unroll
                for (int c = 0; c < 16; ++c) aV[c] = fmaf(hv, wr[c], aV[c]);
                const float* waH = sh.m.wA[kw + kk];
                const float* waC = sh.m.wA[256 + kw + kk];
                #pragma unroll
                for (int i = 0; i < 4; ++i) aA[i] = fmaf(hv, waH[i], fmaf(cv, waC[i], aA[i]));
            }
            #pragma unroll
            for (int c = 0; c < 16; ++c) atomicAdd(&sh.m.V[b][c], aV[c]);
            #pragma unroll
            for (int i = 0; i < 4; ++i) atomicAdd(&sh.m.ap[b][i], aA[i]);
        }
        __syncthreads();   // S3

        // ---- wave 0: publish j partial, arrive dj[t], poll, gather, softmax ----
        if (tid < 64) {
            float pj = 0.0f;
            #pragma unroll
            for (int i = 0; i < 4; ++i)
                pj += tanhf(sh.m.ap[tid][i] + sh.m.ba[i]) * sh.m.v4[i];
            st_rlx_f32(pJs + g * 64 + tid, pj);
            waitcnt_vm();                       // wave-0 stores ack'd at LLC
            if (tid == 0) {
                add_rlx_u32(dj_t, 1u);
                while (ld_rlx_u32(dj_t) < (unsigned)G) __builtin_amdgcn_s_sleep(1);
            }
        }
        __syncthreads();   // S4 (gate pJ reads behind the poll)
        if (tid < 64) {
            float jv = 0.0f;
            #pragma unroll
            for (int gg = 0; gg < 64; ++gg) jv += ld_rlx_f32(pJs + gg * 64 + tid);
            float mx = jv;
            #pragma unroll
            for (int off = 32; off; off >>= 1) mx = fmaxf(mx, __shfl_xor(mx, off));
            const float e = expf(jv - mx);
            float ssum = e;
            #pragma unroll
            for (int off = 32; off; off >>= 1) ssum += __shfl_xor(ssum, off);
            sh.m.s[tid] = e / ssum;
        }
        __syncthreads();   // S5

        // ---- gates + LSTM update (LDS only; staging for wave-0 publish) ----
        if (tid < 256) {
            const int oi = tid >> 6;
            const int bb = tid & 63;
            const float sb = sh.m.s[bb];
            const float pI = fmaf(sb, sh.m.U[bb][0  + oi], sh.m.V[bb][0  + oi]) + sh.m.bg[0  + oi];
            const float pF = fmaf(sb, sh.m.U[bb][4  + oi], sh.m.V[bb][4  + oi]) + sh.m.bg[4  + oi];
            const float pG = fmaf(sb, sh.m.U[bb][8  + oi], sh.m.V[bb][8  + oi]) + sh.m.bg[8  + oi];
            const float pO = fmaf(sb, sh.m.U[bb][12 + oi], sh.m.V[bb][12 + oi]) + sh.m.bg[12 + oi];
            const float cold = sh.m.c_own[oi][bb];
            const float cnew = sigmoidf_(pF) * cold + sigmoidf_(pI) * tanhf(pG);
            const float hnew = sigmoidf_(pO) * tanhf(cnew);
            sh.m.c_own[oi][bb] = cnew;
            sh.m.outst[bb][oi] = hnew;
        }
        __syncthreads();   // S6

        // ---- wave 0 publishes state (uncached), arrives dh[t]; writes out ----
        if (tid < 64) {
            #pragma unroll
            for (int oi = 0; oi < 4; ++oi) {
                st_rlx_f32(hT + (size_t)(4 * g + oi) * B + tid, sh.m.outst[tid][oi]);
                st_rlx_f32(cT + (size_t)(4 * g + oi) * B + tid, sh.m.c_own[oi][tid]);
            }
            waitcnt_vm();                       // state at LLC before flag
            if (tid == 0) add_rlx_u32(dh_t, 1u);
            const float4 v = *(const float4*)sh.m.outst[tid];
            *(float4*)(out + (size_t)t * HB + (size_t)tid * H + 4 * g) = v;
        }
    }
}

extern "C" void kernel_launch(void* const* d_in, const int* in_sizes, int n_in,
                              void* d_out, int out_size, void* d_ws, size_t ws_size,
                              hipStream_t stream) {
    const float* x    = (const float*)d_in[0];
    const float* W_b  = (const float*)d_in[1];
    const float* b_b  = (const float*)d_in[2];
    const float* v_b  = (const float*)d_in[3];
    const float* W_e  = (const float*)d_in[4];
    const float* b_e  = (const float*)d_in[5];
    const float* W_ih = (const float*)d_in[6];
    const float* W_hh = (const float*)d_in[7];
    const float* b_ih = (const float*)d_in[8];
    const float* b_hh = (const float*)d_in[9];
    float* out = (float*)d_out;
    float* wsf = (float*)d_ws;

    // zero the one-time barrier counter (counters/state zeroed in-kernel)
    hipMemsetAsync(d_ws, 0, 64, stream);

    void* args[] = { &x, &W_b, &b_b, &v_b, &W_e, &b_e, &W_ih, &W_hh, &b_ih, &b_hh,
                     &out, &wsf };
    hipLaunchCooperativeKernel((void*)scan_kernel, dim3(G), dim3(NTH), args, 0, stream);
}